// Round 1
// 82.161 us; speedup vs baseline: 1.0220x; 1.0220x over previous
//
#include <hip/hip_runtime.h>

#define K      32
#define KH     16                   // bins per lane (K split across lane pairs)
#define TPB    256
#define NB     2048                 // blocks: 2048 * 128 pair-slots * 8 = N
#define EPT    8                    // elements per pair-slot
#define NTOT   (32 * 64 * 1024)     // 2,097,152
#define PSTRIDE (NB * (TPB / 2))    // 262144 pair-slots per sweep

__device__ __forceinline__ float wave_reduce_sum(float v) {
#pragma unroll
  for (int m = 1; m < 64; m <<= 1) v += __shfl_xor(v, m, 64);
  return v;
}

// xor-1 neighbor add via DPP quad_perm(1,0,3,2): VALU-only, no LDS pipe.
__device__ __forceinline__ float dpp_xor1_add(float v) {
  int sw = __builtin_amdgcn_update_dpp(0, __builtin_bit_cast(int, v),
                                       0xB1, 0xF, 0xF, true);
  return v + __builtin_bit_cast(float, sw);
}
// xor-2 via quad_perm(2,3,0,1) = 0x4E
__device__ __forceinline__ float dpp_xor2_add(float v) {
  int sw = __builtin_amdgcn_update_dpp(0, __builtin_bit_cast(int, v),
                                       0x4E, 0xF, 0xF, true);
  return v + __builtin_bit_cast(float, sw);
}
// xor-8 via row_ror:8 (rotation by 8 within a 16-lane row == lane^8) = 0x128
__device__ __forceinline__ float dpp_xor8_add(float v) {
  int sw = __builtin_amdgcn_update_dpp(0, __builtin_bit_cast(int, v),
                                       0x128, 0xF, 0xF, true);
  return v + __builtin_bit_cast(float, sw);
}

// reduce across lanes of the SAME parity (32 lanes): masks 2,4,8,16,32.
// 2 and 8 are DPP (VALU); 4,16,32 stay shfl (no xor-DPP exists for them).
__device__ __forceinline__ float pair_lane_reduce(float v) {
  v = dpp_xor2_add(v);
  v += __shfl_xor(v, 4, 64);
  v = dpp_xor8_add(v);
  v += __shfl_xor(v, 16, 64);
  v += __shfl_xor(v, 32, 64);
  return v;
}

// Theory this round: the 84us was latency, not issue. Two structural bugs:
// (1) xs[EPT] read with runtime index inside the '#pragma unroll 1' e-loop
//     -> SROA fails -> whole array scratch-demoted: 8 scratch stores + one
//     exposed-latency scratch load per iteration (rule-#20 class).
//     Fix: direct load + NAMED-SCALAR 1-deep prefetch, no arrays.
// (2) per-e __shfl_xor(..,1) -> ds_bpermute (LDS pipe, lgkm wait) on the
//     serial chain exp2->s_loc->exchange->rcp->fmas. Fix: DPP quad_perm add.
// Also: 4-way accumulation chains (was 2) to halve serial add depth.
// e-loop stays 'unroll 1' (only proven-safe setting for the allocator).
__global__ __launch_bounds__(TPB)
void ssq_main(const float* __restrict__ x, const float* __restrict__ bins,
              float* __restrict__ out, float* __restrict__ partials) {
  const int tid  = threadIdx.x;
  const int half = tid & 1;                       // which 16-bin half
  const int pslot = blockIdx.x * (TPB / 2) + (tid >> 1);

  // this lane's 16 bins (VGPRs -- parity-dependent, can't be SGPR)
  float binv[KH];
#pragma unroll
  for (int j = 0; j < KH; ++j) binv[j] = bins[KH * half + j];
  float bs_local = 0.f;
#pragma unroll
  for (int j = 0; j < KH; ++j) bs_local += binv[j];
  const float binsum = dpp_xor1_add(bs_local);
  const float epsb = 1e-10f * binsum;             // eps * sum(bins) term

  float sAcc[KH];
#pragma unroll
  for (int j = 0; j < KH; ++j) sAcc[j] = 0.f;
  float q = 0.f;

  const float Ch = -7.213475204444817f;           // 0.5 * ALPHA * log2(e)

  float xv_cur = x[pslot];                        // 1-deep prefetch scalar

#pragma unroll 1
  for (int e = 0; e < EPT; ++e) {
    const float xv = xv_cur;
    if (e + 1 < EPT) xv_cur = x[pslot + (e + 1) * PSTRIDE];  // uniform branch
    float t[KH];                                  // static indices only
    float s0 = 0.f, s1 = 0.f, s2 = 0.f, s3 = 0.f;
    float h0 = 0.f, h1 = 0.f, h2 = 0.f, h3 = 0.f;
    float b0 = 0.f, b1 = 0.f, b2 = 0.f, b3 = 0.f;
#pragma unroll
    for (int j = 0; j < KH; j += 4) {
      float ha = __builtin_amdgcn_exp2f(Ch * fabsf(xv - binv[j + 0]));
      float hb = __builtin_amdgcn_exp2f(Ch * fabsf(xv - binv[j + 1]));
      float hc = __builtin_amdgcn_exp2f(Ch * fabsf(xv - binv[j + 2]));
      float hd = __builtin_amdgcn_exp2f(Ch * fabsf(xv - binv[j + 3]));
      float ta = ha * ha, tb = hb * hb, tc = hc * hc, td = hd * hd;
      t[j + 0] = ta; t[j + 1] = tb; t[j + 2] = tc; t[j + 3] = td;
      s0 += ta; s1 += tb; s2 += tc; s3 += td;
      h0 += ha; h1 += hb; h2 += hc; h3 += hd;
      b0 = fmaf(ta, binv[j + 0], b0);
      b1 = fmaf(tb, binv[j + 1], b1);
      b2 = fmaf(tc, binv[j + 2], b2);
      b3 = fmaf(td, binv[j + 3], b3);
    }
    const float s_loc = (s0 + s1) + (s2 + s3);
    const float b_loc = (b0 + b1) + (b2 + b3);
    const float s_full = dpp_xor1_add(s_loc);     // both halves, VALU-only
    const float b_full = dpp_xor1_add(b_loc);
    const float inv = __builtin_amdgcn_rcpf(s_full);
    // local hsum * rsqrt(s): summing q over ALL lanes later gives sum_k sqrt(a_k)
    q = fmaf((h0 + h1) + (h2 + h3), __builtin_amdgcn_rsqf(s_full), q);
    if (half == 0) out[pslot + e * PSTRIDE] = fmaf(b_full, inv, epsb);
#pragma unroll
    for (int j = 0; j < KH; ++j) sAcc[j] = fmaf(t[j], inv, sAcc[j]);
  }

  // block reduction. Same-parity butterfly: after it, lane0 holds bin j sum,
  // lane1 holds bin j+16 sum (for each of the 16 j's). q: full-wave reduce.
  __shared__ float red[4][K + 1];
  const int lane = tid & 63, wv = tid >> 6;
#pragma unroll
  for (int j = 0; j < KH; ++j) {
    float v = pair_lane_reduce(sAcc[j]);
    if (lane < 2) red[wv][KH * lane + j] = v;     // lane==half here
  }
  {
    float v = wave_reduce_sum(q);
    if (lane == 0) red[wv][K] = v;
  }
  __syncthreads();
  if (tid < K + 1) {
    float v = red[0][tid] + red[1][tid] + red[2][tid] + red[3][tid];
    partials[tid * NB + blockIdx.x] = v;          // written exactly once
  }
}

// 33 blocks: block c reduces partials[c*NB .. c*NB+NB) -> sums[c]
__global__ __launch_bounds__(TPB)
void ssq_reduce(const float* __restrict__ partials, float* __restrict__ sums) {
  const float* p = partials + blockIdx.x * NB;
  const int tid  = threadIdx.x;
  float s = 0.f;
#pragma unroll
  for (int j = 0; j < NB / TPB; ++j) s += p[tid + j * TPB];
  s = wave_reduce_sum(s);
  __shared__ float red[4];
  if ((tid & 63) == 0) red[tid >> 6] = s;
  __syncthreads();
  if (tid == 0) sums[blockIdx.x] = red[0] + red[1] + red[2] + red[3];
}

// one wave: entropy over 32 p_k + quant mean + tails
__global__ void ssq_final(const float* __restrict__ sums, float* __restrict__ out) {
  const int lane = threadIdx.x;
  float e = 0.f;
  if (lane < K) {
    float p = sums[lane] * (1.0f / (float)NTOT) + 1e-10f;  // eps folded in here
    e = -p * __logf(p);
  }
  e = wave_reduce_sum(e);
  if (lane == 0) {
    out[NTOT + 0] = e;                              // code entropy
    out[NTOT + 1] = 0.f;                            // TAU
    out[NTOT + 2] = sums[K] * (1.0f / (float)NTOT); // quant loss
    out[NTOT + 3] = 0.f;                            // TAU2
  }
}

extern "C" void kernel_launch(void* const* d_in, const int* in_sizes, int n_in,
                              void* d_out, int out_size, void* d_ws, size_t ws_size,
                              hipStream_t stream) {
  const float* x    = (const float*)d_in[0];
  const float* bins = (const float*)d_in[1];
  float* out        = (float*)d_out;
  float* partials   = (float*)d_ws;                 // (K+1)*NB floats = 264 KB
  float* sums       = partials + (K + 1) * NB;      // 33 floats

  ssq_main  <<<NB,    TPB, 0, stream>>>(x, bins, out, partials);
  ssq_reduce<<<K + 1, TPB, 0, stream>>>(partials, sums);
  ssq_final <<<1,     64,  0, stream>>>(sums, out);
}